// Round 1
// 285.378 us; speedup vs baseline: 1.1505x; 1.1505x over previous
//
#include <hip/hip_runtime.h>
#include <hip/hip_bf16.h>

// Reassociated Tucker pipeline (fp32 in/out; bf16 internally):
//   y[b,t,o] = sum_j Z[b,t,j] * M[t,j,o]
//     Z[b,t,j] = sum_i x[b,t,i]   * in_core[i,j]      <- t-independent! contiguous GEMM
//     M[t,j,o] = sum_k W1[t,j,k]  * out_core[o,k]
//     W1[t,j,k]= sum_m task[t,m]  * tensor[m,j,k]
//
//   K1 : W1[t][j][k]                       (bf16, 64 KB)
//   KT : icT[j][i] = in_core^T             (bf16, 512 KB)
//   K2 : M_T[t][o][j] (MFMA)               (bf16, 4 MB)
//   K0 : pp[ks][row][64] = X[8192][4096] * icT^T, K-split, LDS-staged x rows
//        -> every x global load is 256B-contiguous per row (fixes the 128KB-stride
//           64B-granule pattern that held old k2_p2 at 938 GB/s / 11.7% HBM)
//   KR : Z[8192][64] = bf16(sum_ks pp)
//   K3 : y = Z * M_T[t]  with LDS-transpose epilogue -> 512B-contiguous y stores

typedef __bf16 bf16;
typedef __bf16 bf16x8 __attribute__((ext_vector_type(8)));
typedef __bf16 bf16x4 __attribute__((ext_vector_type(4)));
typedef float  f32x4  __attribute__((ext_vector_type(4)));

__device__ __forceinline__ bf16x8 load_frag_bf16(const bf16* p) {
    return *reinterpret_cast<const bf16x8*>(p);
}

__device__ __forceinline__ bf16x8 load_frag_f32(const float* p) {
    f32x4 a = *reinterpret_cast<const f32x4*>(p);
    f32x4 b = *reinterpret_cast<const f32x4*>(p + 4);
    bf16x8 r;
    r[0] = (bf16)a[0]; r[1] = (bf16)a[1]; r[2] = (bf16)a[2]; r[3] = (bf16)a[3];
    r[4] = (bf16)b[0]; r[5] = (bf16)b[1]; r[6] = (bf16)b[2]; r[7] = (bf16)b[3];
    return r;
}

__device__ __forceinline__ f32x4 mfma16(bf16x8 a, bf16x8 b, f32x4 c) {
    return __builtin_amdgcn_mfma_f32_16x16x32_bf16(a, b, c, 0, 0, 0);
}

// ---------------------------------------------------------------- K1
// grid 128 x 256. W1[t][j][k] = sum_m task[t][m]*tensor[m][j][k]. fp32 math.
__global__ __launch_bounds__(256) void k1_w1(
    const float* __restrict__ task,   // [8][64]
    const float* __restrict__ tensor, // [64][64][64] (m, j, k)
    bf16* __restrict__ w1)            // [8][64][64]  (t, j, k)
{
    int t    = blockIdx.x >> 4;
    int part = blockIdx.x & 15;
    int idx  = part * 256 + threadIdx.x;  // 0..4095
    int j    = idx >> 6;
    int k    = idx & 63;                  // lanes consecutive in k -> coalesced
    float acc = 0.f;
    #pragma unroll 8
    for (int m = 0; m < 64; ++m)
        acc += task[t * 64 + m] * tensor[(m * 64 + j) * 64 + k];
    w1[(t * 64 + j) * 64 + k] = (bf16)acc;
}

// ---------------------------------------------------------------- KT
// grid 128 x 256. icT[j][i] = bf16(in_core[i][j]). Writes 16B-contiguous,
// lanes consecutive in i -> 1KB-contiguous stores. Reads hit L2 (1 MB src).
__global__ __launch_bounds__(256) void kt_ict(
    const float* __restrict__ in_core, // [4096][64] (i, j)
    bf16* __restrict__ icT)            // [64][4096] (j, i)
{
    int idx = blockIdx.x * 256 + threadIdx.x; // 0..32767
    int i0  = (idx & 511) * 8;
    int j   = idx >> 9;
    bf16x8 v;
    #pragma unroll
    for (int s = 0; s < 8; ++s)
        v[s] = (bf16)in_core[(size_t)(i0 + s) * 64 + j];
    *reinterpret_cast<bf16x8*>(icT + (size_t)j * 4096 + i0) = v;
}

// ---------------------------------------------------------------- K2
// grid 512 x 256. M_T[t][o][j] = sum_k out_core[o][k]*W1[t][j][k].
// Per t: M=4096(o), N=64(j), K=64. Wave: 16 o-rows x 64 j.
__global__ __launch_bounds__(256) void k2_mt(
    const float* __restrict__ out_core, // [4096][64] (o, k) fp32
    const bf16* __restrict__ w1,        // [8][64][64] (t, j, k)
    bf16* __restrict__ mt)              // [8][4096][64] (t, o, j)
{
    int t    = blockIdx.x >> 6;
    int ot   = blockIdx.x & 63;
    int wave = threadIdx.x >> 6;
    int lane = threadIdx.x & 63;
    int m    = lane & 15;
    int q    = lane >> 4;
    int o0   = ot * 64 + wave * 16;

    f32x4 acc[4] = {};
    #pragma unroll
    for (int kc = 0; kc < 64; kc += 32) {
        bf16x8 a = load_frag_f32(out_core + (size_t)(o0 + m) * 64 + kc + q * 8);
        #pragma unroll
        for (int nt = 0; nt < 4; ++nt) {
            bf16x8 b = load_frag_bf16(w1 + (size_t)(t * 64 + nt * 16 + m) * 64 + kc + q * 8);
            acc[nt] = mfma16(a, b, acc[nt]);
        }
    }
    #pragma unroll
    for (int nt = 0; nt < 4; ++nt) {
        #pragma unroll
        for (int r = 0; r < 4; ++r) {
            int o = o0 + q * 4 + r;                  // C/D row = quad*4 + reg
            mt[(size_t)(t * 4096 + o) * 64 + nt * 16 + m] = (bf16)acc[nt][r];
        }
    }
}

// ---------------------------------------------------------------- K0
// grid (512*KS) x 256. Z-partials: C[16 rows][64 j], K-split over i=4096.
// X rows are consecutive (b,t) rows -> contiguous. BK=256 f32 staged in LDS
// (bf16, XOR-swizzled: 16B-unit u ^= (row&7); balanced banks on b64 write
// and b128 read). T14 issue-early: next tile's global loads issued before
// this tile's MFMA.
__global__ __launch_bounds__(256) void k0_z(
    const float* __restrict__ x,   // [8192][4096] fp32 (rows = b*8+t)
    const bf16* __restrict__ icT,  // [64][4096] (j, i)
    float* __restrict__ pp,        // [KS][8192][64] f32 partials
    int kchunk)                    // 4096 / KS, multiple of 256
{
    __shared__ bf16 xs[16 * 256];  // 8 KB -> 8 blocks/CU, 32 waves/CU
    int ks       = blockIdx.x >> 9;
    int mt       = blockIdx.x & 511;
    int row_base = mt * 16;
    int kbeg     = ks * kchunk;
    int tid  = threadIdx.x;
    int r    = tid >> 4;           // staging row 0..15
    int c16  = tid & 15;           // staging col group
    int wave = tid >> 6;
    int lane = tid & 63;
    int m    = lane & 15;
    int q    = lane >> 4;
    int n0   = wave * 16;          // j-range of this wave

    const float* gsrc = x   + (size_t)(row_base + r) * 4096 + kbeg;
    const bf16*  bbas = icT + (size_t)(n0 + m) * 4096 + kbeg;

    // preload tile 0: per instr 4 rows x 256B contiguous
    f32x4 v[4];
    #pragma unroll
    for (int i = 0; i < 4; ++i)
        v[i] = *reinterpret_cast<const f32x4*>(gsrc + c16 * 4 + i * 64);

    f32x4 acc = {};
    for (int kc = 0; kc < kchunk; kc += 256) {
        __syncthreads();           // previous tile's LDS reads done
        #pragma unroll
        for (int i = 0; i < 4; ++i) {
            bf16x4 w;
            w[0] = (bf16)v[i][0]; w[1] = (bf16)v[i][1];
            w[2] = (bf16)v[i][2]; w[3] = (bf16)v[i][3];
            int col = c16 * 4 + i * 64;
            int u   = (col >> 3) ^ (r & 7);          // XOR swizzle, 16B units
            *reinterpret_cast<bf16x4*>(&xs[r * 256 + u * 8 + (col & 7)]) = w;
        }
        __syncthreads();
        if (kc + 256 < kchunk) {   // issue next tile early (hide HBM latency)
            #pragma unroll
            for (int i = 0; i < 4; ++i)
                v[i] = *reinterpret_cast<const f32x4*>(gsrc + kc + 256 + c16 * 4 + i * 64);
        }
        #pragma unroll
        for (int c = 0; c < 8; ++c) {
            int u = (c * 4 + q) ^ (m & 7);
            bf16x8 a = *reinterpret_cast<const bf16x8*>(&xs[m * 256 + u * 8]);
            bf16x8 b = load_frag_bf16(bbas + kc + c * 32 + q * 8);  // L2-resident
            acc = mfma16(a, b, acc);
        }
    }
    float* dst = pp + (size_t)ks * 524288 + (size_t)row_base * 64;
    #pragma unroll
    for (int rr = 0; rr < 4; ++rr)
        dst[(q * 4 + rr) * 64 + n0 + m] = acc[rr];
}

// ---------------------------------------------------------------- KR
// grid 512 x 256. Z = bf16(sum over splits of pp). 4 elems/thread.
__global__ __launch_bounds__(256) void k_reduce(
    const float* __restrict__ pp,  // [nsplit][524288]
    bf16* __restrict__ z,          // [524288] = [8192][64]
    int nsplit)
{
    int idx = (blockIdx.x * 256 + threadIdx.x) * 4;
    f32x4 s = *reinterpret_cast<const f32x4*>(pp + idx);
    for (int sp = 1; sp < nsplit; ++sp)
        s += *reinterpret_cast<const f32x4*>(pp + (size_t)sp * 524288 + idx);
    bf16x4 o;
    o[0] = (bf16)s[0]; o[1] = (bf16)s[1]; o[2] = (bf16)s[2]; o[3] = (bf16)s[3];
    *reinterpret_cast<bf16x4*>(z + idx) = o;
}

// ---------------------------------------------------------------- K3
// grid 2048 x 256. Per t: M=1024(b), N=4096(o), K=64(j). Block 128x128 tile;
// wave: 32 rows x 128 cols. Epilogue: per-wave LDS slab transpose so y stores
// are f32x4 with 512B contiguous per row per instruction (old k4 stored 64B
// granules at 128KB row stride -> DRAM-inefficient).
__global__ __launch_bounds__(256) void k3_y(
    const bf16* __restrict__ z,   // [8192][64] (rows = b*8+t)
    const bf16* __restrict__ mt,  // [8][4096][64] (t, o, j)
    float* __restrict__ y)        // [1024][8][4096] fp32
{
    __shared__ float slab[4 * 2112];  // 4 waves x 16 rows x stride 132 (2-way max)
    int bx    = blockIdx.x;
    int t     = bx >> 8;          // 256 blocks per t
    int rest  = bx & 255;
    int mtile = rest >> 5;        // 0..7
    int ntile = rest & 31;        // 0..31
    int wave  = threadIdx.x >> 6;
    int lane  = threadIdx.x & 63;
    int m     = lane & 15;
    int q     = lane >> 4;

    int b_base = mtile * 128 + wave * 32;
    int n_base = ntile * 128;

    f32x4 acc[2][8] = {};
    #pragma unroll
    for (int kc = 0; kc < 64; kc += 32) {
        bf16x8 a0 = load_frag_bf16(z + (size_t)((b_base + m) * 8 + t) * 64 + kc + q * 8);
        bf16x8 a1 = load_frag_bf16(z + (size_t)((b_base + 16 + m) * 8 + t) * 64 + kc + q * 8);
        #pragma unroll
        for (int nt = 0; nt < 8; ++nt) {
            bf16x8 b = load_frag_bf16(mt + (size_t)(t * 4096 + n_base + nt * 16 + m) * 64 + kc + q * 8);
            acc[0][nt] = mfma16(a0, b, acc[0][nt]);
            acc[1][nt] = mfma16(a1, b, acc[1][nt]);
        }
    }

    float* sw = slab + wave * 2112;
    #pragma unroll
    for (int sub = 0; sub < 2; ++sub) {
        #pragma unroll
        for (int nt = 0; nt < 8; ++nt) {
            #pragma unroll
            for (int r = 0; r < 4; ++r)
                sw[(q * 4 + r) * 132 + nt * 16 + m] = acc[sub][nt][r];
        }
        __syncthreads();
        #pragma unroll
        for (int p = 0; p < 8; ++p) {
            int row = 2 * p + (lane >> 5);     // 2 rows x 512B contiguous / instr
            int cu  = lane & 31;
            f32x4 d = *reinterpret_cast<const f32x4*>(sw + row * 132 + cu * 4);
            int b   = b_base + sub * 16 + row;
            *reinterpret_cast<f32x4*>(y + (size_t)(b * 8 + t) * 4096 + n_base + cu * 4) = d;
        }
        __syncthreads();
    }
}

// ----------------------------------------------------------------
extern "C" void kernel_launch(void* const* d_in, const int* in_sizes, int n_in,
                              void* d_out, int out_size, void* d_ws, size_t ws_size,
                              hipStream_t stream) {
    // setup_inputs order: x, tensor_core, task_core, in_core, out_core (all fp32)
    const float* x        = (const float*)d_in[0];
    const float* tensor_c = (const float*)d_in[1];
    const float* task_c   = (const float*)d_in[2];
    const float* in_c     = (const float*)d_in[3];
    const float* out_c    = (const float*)d_in[4];
    float* y = (float*)d_out;

    // Workspace layout (bytes):
    //   w1: 64 KB | icT: 512 KB | M_T: 4 MB | Z: 1 MB | pp: KS*2 MB f32
    char* ws = (char*)d_ws;
    bf16*  w1  = (bf16*)ws;
    bf16*  icT = (bf16*)(ws + (64 << 10));
    bf16*  mtc = (bf16*)(ws + (64 << 10) + (512 << 10));
    bf16*  zb  = (bf16*)(ws + (64 << 10) + (512 << 10) + (4 << 20));
    float* pp  = (float*)(ws + (64 << 10) + (512 << 10) + (4 << 20) + (1 << 20));

    size_t fixed = (size_t)(64 << 10) + (512 << 10) + (4 << 20) + (1 << 20);
    int KS = 4;
    while (KS > 1 && fixed + (size_t)KS * 2097152 > ws_size) KS >>= 1;
    int kchunk = 4096 / KS;

    k1_w1   <<<128,      256, 0, stream>>>(task_c, tensor_c, w1);
    kt_ict  <<<128,      256, 0, stream>>>(in_c, icT);
    k2_mt   <<<512,      256, 0, stream>>>(out_c, w1, mtc);
    k0_z    <<<512 * KS, 256, 0, stream>>>(x, icT, pp, kchunk);
    k_reduce<<<512,      256, 0, stream>>>(pp, zb, KS);
    k3_y    <<<2048,     256, 0, stream>>>(zb, mtc, y);
}

// Round 2
// 281.158 us; speedup vs baseline: 1.1678x; 1.0150x over previous
//
#include <hip/hip_runtime.h>
#include <hip/hip_bf16.h>

// Reassociated Tucker pipeline (fp32 in/out; bf16 internally):
//   y[b,t,o] = sum_j Z[b,t,j] * M[t,j,o]
//     Z[b,t,j] = sum_i x[b,t,i]   * in_core[i,j]      <- t-independent, contiguous GEMM
//     M[t,j,o] = sum_k W1[t,j,k]  * out_core[o,k]
//     W1[t,j,k]= sum_m task[t,m]  * tensor[m,j,k]
//
// v3 (this round): KS=1 (drop pp f32 partials + k_reduce; -16 MB traffic),
// depth-2 register prefetch in k0 to keep HBM latency hidden at 2 blocks/CU,
// k1+kt merged into one k_setup dispatch, k3_y barrier-free wave-private
// epilogue. 4 dispatches total:
//   K_SETUP : W1[t][j][k] (64 KB) + icT[j][i]=in_core^T (512 KB)
//   K2      : M_T[t][o][j] (MFMA, 4 MB)
//   K0      : Z[8192][64] = X[8192][4096] * icT^T   (LDS-staged, XOR-swizzled)
//   K3      : y = Z * M_T[t]  (LDS-transpose epilogue -> 512B-contiguous stores)

typedef __bf16 bf16;
typedef __bf16 bf16x8 __attribute__((ext_vector_type(8)));
typedef __bf16 bf16x4 __attribute__((ext_vector_type(4)));
typedef float  f32x4  __attribute__((ext_vector_type(4)));

__device__ __forceinline__ bf16x8 load_frag_bf16(const bf16* p) {
    return *reinterpret_cast<const bf16x8*>(p);
}

__device__ __forceinline__ bf16x8 load_frag_f32(const float* p) {
    f32x4 a = *reinterpret_cast<const f32x4*>(p);
    f32x4 b = *reinterpret_cast<const f32x4*>(p + 4);
    bf16x8 r;
    r[0] = (bf16)a[0]; r[1] = (bf16)a[1]; r[2] = (bf16)a[2]; r[3] = (bf16)a[3];
    r[4] = (bf16)b[0]; r[5] = (bf16)b[1]; r[6] = (bf16)b[2]; r[7] = (bf16)b[3];
    return r;
}

__device__ __forceinline__ f32x4 mfma16(bf16x8 a, bf16x8 b, f32x4 c) {
    return __builtin_amdgcn_mfma_f32_16x16x32_bf16(a, b, c, 0, 0, 0);
}

// ---------------------------------------------------------------- K_SETUP
// grid 256 x 256. Blocks 0..127: W1[t][j][k] = sum_m task[t][m]*tensor[m][j][k].
// Blocks 128..255: icT[j][i] = bf16(in_core[i][j]) (16B stores, 1KB runs).
__global__ __launch_bounds__(256) void k_setup(
    const float* __restrict__ task,    // [8][64]
    const float* __restrict__ tensor,  // [64][64][64] (m, j, k)
    const float* __restrict__ in_core, // [4096][64]   (i, j)
    bf16* __restrict__ w1,             // [8][64][64]  (t, j, k)
    bf16* __restrict__ icT)            // [64][4096]   (j, i)
{
    int bid = blockIdx.x;
    if (bid < 128) {
        int t    = bid >> 4;
        int idx  = (bid & 15) * 256 + threadIdx.x;  // 0..4095
        int j    = idx >> 6;
        int k    = idx & 63;                        // lanes consecutive in k
        float acc = 0.f;
        #pragma unroll 8
        for (int m = 0; m < 64; ++m)
            acc += task[t * 64 + m] * tensor[(m * 64 + j) * 64 + k];
        w1[(t * 64 + j) * 64 + k] = (bf16)acc;
    } else {
        int idx = (bid - 128) * 256 + threadIdx.x;  // 0..32767
        int i0  = (idx & 511) * 8;
        int j   = idx >> 9;
        bf16x8 v;
        #pragma unroll
        for (int s = 0; s < 8; ++s)
            v[s] = (bf16)in_core[(size_t)(i0 + s) * 64 + j];
        *reinterpret_cast<bf16x8*>(icT + (size_t)j * 4096 + i0) = v;
    }
}

// ---------------------------------------------------------------- K2
// grid 512 x 256. M_T[t][o][j] = sum_k out_core[o][k]*W1[t][j][k].
// Per t: M=4096(o), N=64(j), K=64. Wave: 16 o-rows x 64 j.
__global__ __launch_bounds__(256) void k2_mt(
    const float* __restrict__ out_core, // [4096][64] (o, k) fp32
    const bf16* __restrict__ w1,        // [8][64][64] (t, j, k)
    bf16* __restrict__ mt)              // [8][4096][64] (t, o, j)
{
    int t    = blockIdx.x >> 6;
    int ot   = blockIdx.x & 63;
    int wave = threadIdx.x >> 6;
    int lane = threadIdx.x & 63;
    int m    = lane & 15;
    int q    = lane >> 4;
    int o0   = ot * 64 + wave * 16;

    f32x4 acc[4] = {};
    #pragma unroll
    for (int kc = 0; kc < 64; kc += 32) {
        bf16x8 a = load_frag_f32(out_core + (size_t)(o0 + m) * 64 + kc + q * 8);
        #pragma unroll
        for (int nt = 0; nt < 4; ++nt) {
            bf16x8 b = load_frag_bf16(w1 + (size_t)(t * 64 + nt * 16 + m) * 64 + kc + q * 8);
            acc[nt] = mfma16(a, b, acc[nt]);
        }
    }
    #pragma unroll
    for (int nt = 0; nt < 4; ++nt) {
        #pragma unroll
        for (int r = 0; r < 4; ++r) {
            int o = o0 + q * 4 + r;                  // C/D row = quad*4 + reg
            mt[(size_t)(t * 4096 + o) * 64 + nt * 16 + m] = (bf16)acc[nt][r];
        }
    }
}

// ---------------------------------------------------------------- K0
// grid 512 x 256. Z[16 rows][64 j] per block, full K=4096, no K-split.
// BK=256 f32 staged in LDS (bf16, XOR-swizzled: 16B-unit u ^= (row&7)).
// Depth-2 register prefetch (vA/vB, manual 2x unroll): 8 x f32x4 in flight
// per thread covers HBM latency at 2 blocks/CU. Per global-load instr:
// 4 rows x 256B contiguous.
__global__ __launch_bounds__(256) void k0_z(
    const float* __restrict__ x,   // [8192][4096] fp32 (rows = b*8+t)
    const bf16* __restrict__ icT,  // [64][4096] (j, i)
    bf16* __restrict__ z)          // [8192][64]
{
    __shared__ bf16 xs[16 * 256];  // 8 KB
    int row_base = blockIdx.x * 16;
    int tid  = threadIdx.x;
    int r    = tid >> 4;           // staging row 0..15
    int c16  = tid & 15;           // staging col group
    int wave = tid >> 6;
    int lane = tid & 63;
    int m    = lane & 15;
    int q    = lane >> 4;
    int n0   = wave * 16;          // j-range of this wave

    const float* gsrc = x   + (size_t)(row_base + r) * 4096;
    const bf16*  bbas = icT + (size_t)(n0 + m) * 4096;

    f32x4 vA[4], vB[4];
    #pragma unroll
    for (int i = 0; i < 4; ++i)
        vA[i] = *reinterpret_cast<const f32x4*>(gsrc + c16 * 4 + i * 64);
    #pragma unroll
    for (int i = 0; i < 4; ++i)
        vB[i] = *reinterpret_cast<const f32x4*>(gsrc + 256 + c16 * 4 + i * 64);

    f32x4 acc = {};
    #pragma unroll 1
    for (int kc = 0; kc < 4096; kc += 512) {
        // ---- half A: compute tile kc from vA, prefetch kc+512 into vA
        __syncthreads();           // previous tile's LDS reads done
        #pragma unroll
        for (int i = 0; i < 4; ++i) {
            bf16x4 w;
            w[0] = (bf16)vA[i][0]; w[1] = (bf16)vA[i][1];
            w[2] = (bf16)vA[i][2]; w[3] = (bf16)vA[i][3];
            int col = c16 * 4 + i * 64;
            int u   = (col >> 3) ^ (r & 7);          // XOR swizzle, 16B units
            *reinterpret_cast<bf16x4*>(&xs[r * 256 + u * 8 + (col & 7)]) = w;
        }
        __syncthreads();
        if (kc + 512 < 4096) {
            #pragma unroll
            for (int i = 0; i < 4; ++i)
                vA[i] = *reinterpret_cast<const f32x4*>(gsrc + kc + 512 + c16 * 4 + i * 64);
        }
        #pragma unroll
        for (int c = 0; c < 8; ++c) {
            int u = (c * 4 + q) ^ (m & 7);
            bf16x8 a = *reinterpret_cast<const bf16x8*>(&xs[m * 256 + u * 8]);
            bf16x8 b = load_frag_bf16(bbas + kc + c * 32 + q * 8);  // L2-resident
            acc = mfma16(a, b, acc);
        }
        // ---- half B: compute tile kc+256 from vB, prefetch kc+768 into vB
        __syncthreads();
        #pragma unroll
        for (int i = 0; i < 4; ++i) {
            bf16x4 w;
            w[0] = (bf16)vB[i][0]; w[1] = (bf16)vB[i][1];
            w[2] = (bf16)vB[i][2]; w[3] = (bf16)vB[i][3];
            int col = c16 * 4 + i * 64;
            int u   = (col >> 3) ^ (r & 7);
            *reinterpret_cast<bf16x4*>(&xs[r * 256 + u * 8 + (col & 7)]) = w;
        }
        __syncthreads();
        if (kc + 768 < 4096) {
            #pragma unroll
            for (int i = 0; i < 4; ++i)
                vB[i] = *reinterpret_cast<const f32x4*>(gsrc + kc + 768 + c16 * 4 + i * 64);
        }
        #pragma unroll
        for (int c = 0; c < 8; ++c) {
            int u = (c * 4 + q) ^ (m & 7);
            bf16x8 a = *reinterpret_cast<const bf16x8*>(&xs[m * 256 + u * 8]);
            bf16x8 b = load_frag_bf16(bbas + kc + 256 + c * 32 + q * 8);
            acc = mfma16(a, b, acc);
        }
    }
    bf16* dst = z + (size_t)row_base * 64;
    #pragma unroll
    for (int rr = 0; rr < 4; ++rr)
        dst[(q * 4 + rr) * 64 + n0 + m] = (bf16)acc[rr];
}

// ---------------------------------------------------------------- K3
// grid 2048 x 256. Per t: M=1024(b), N=4096(o), K=64(j). Block 128x128 tile;
// wave: 32 rows x 128 cols. Epilogue: WAVE-PRIVATE LDS slab transpose (no
// __syncthreads needed; program order + lgkmcnt suffices) so y stores are
// f32x4 with 512B contiguous per row per instruction.
__global__ __launch_bounds__(256) void k3_y(
    const bf16* __restrict__ z,   // [8192][64] (rows = b*8+t)
    const bf16* __restrict__ mt,  // [8][4096][64] (t, o, j)
    float* __restrict__ y)        // [1024][8][4096] fp32
{
    __shared__ float slab[4 * 2112];  // 4 waves x 16 rows x stride 132
    int bx    = blockIdx.x;
    int t     = bx >> 8;          // 256 blocks per t
    int rest  = bx & 255;
    int mtile = rest >> 5;        // 0..7
    int ntile = rest & 31;        // 0..31
    int wave  = threadIdx.x >> 6;
    int lane  = threadIdx.x & 63;
    int m     = lane & 15;
    int q     = lane >> 4;

    int b_base = mtile * 128 + wave * 32;
    int n_base = ntile * 128;

    f32x4 acc[2][8] = {};
    #pragma unroll
    for (int kc = 0; kc < 64; kc += 32) {
        bf16x8 a0 = load_frag_bf16(z + (size_t)((b_base + m) * 8 + t) * 64 + kc + q * 8);
        bf16x8 a1 = load_frag_bf16(z + (size_t)((b_base + 16 + m) * 8 + t) * 64 + kc + q * 8);
        #pragma unroll
        for (int nt = 0; nt < 8; ++nt) {
            bf16x8 b = load_frag_bf16(mt + (size_t)(t * 4096 + n_base + nt * 16 + m) * 64 + kc + q * 8);
            acc[0][nt] = mfma16(a0, b, acc[0][nt]);
            acc[1][nt] = mfma16(a1, b, acc[1][nt]);
        }
    }

    float* sw = slab + wave * 2112;   // wave-private slab
    #pragma unroll
    for (int sub = 0; sub < 2; ++sub) {
        #pragma unroll
        for (int nt = 0; nt < 8; ++nt) {
            #pragma unroll
            for (int r = 0; r < 4; ++r)
                sw[(q * 4 + r) * 132 + nt * 16 + m] = acc[sub][nt][r];
        }
        #pragma unroll
        for (int p = 0; p < 8; ++p) {
            int row = 2 * p + (lane >> 5);     // 2 rows x 512B contiguous / instr
            int cu  = lane & 31;
            f32x4 d = *reinterpret_cast<const f32x4*>(sw + row * 132 + cu * 4);
            int b   = b_base + sub * 16 + row;
            *reinterpret_cast<f32x4*>(y + (size_t)(b * 8 + t) * 4096 + n_base + cu * 4) = d;
        }
    }
}

// ----------------------------------------------------------------
extern "C" void kernel_launch(void* const* d_in, const int* in_sizes, int n_in,
                              void* d_out, int out_size, void* d_ws, size_t ws_size,
                              hipStream_t stream) {
    // setup_inputs order: x, tensor_core, task_core, in_core, out_core (all fp32)
    const float* x        = (const float*)d_in[0];
    const float* tensor_c = (const float*)d_in[1];
    const float* task_c   = (const float*)d_in[2];
    const float* in_c     = (const float*)d_in[3];
    const float* out_c    = (const float*)d_in[4];
    float* y = (float*)d_out;

    // Workspace layout (bytes): w1 64KB | icT 512KB | M_T 4MB | Z 1MB
    char* ws = (char*)d_ws;
    bf16* w1  = (bf16*)ws;
    bf16* icT = (bf16*)(ws + (64 << 10));
    bf16* mtc = (bf16*)(ws + (64 << 10) + (512 << 10));
    bf16* zb  = (bf16*)(ws + (64 << 10) + (512 << 10) + (4 << 20));

    k_setup<<<256,  256, 0, stream>>>(task_c, tensor_c, in_c, w1, icT);
    k2_mt  <<<512,  256, 0, stream>>>(out_c, w1, mtc);
    k0_z   <<<512,  256, 0, stream>>>(x, icT, zb);
    k3_y   <<<2048, 256, 0, stream>>>(zb, mtc, y);
}